// Round 3
// baseline (323.218 us; speedup 1.0000x reference)
//
#include <hip/hip_runtime.h>

// Problem: x (16,32,32,256) fp32 = 4,194,304 elems; 16 centers = linspace(-2,2,step .25).
// Outputs concat flat: qbar[N], qhard[N], qsoft[N], one_hot[N,16].  All fp32.
// Memory-bound: ~319 MB writes (one_hot dominates) + 17 MB reads.

#define NC 16

__global__ __launch_bounds__(256) void quantize_kernel(
    const float* __restrict__ x,
    const float* __restrict__ centers,
    float* __restrict__ out,
    int n)
{
    const int t = blockIdx.x * blockDim.x + threadIdx.x;
    if (t >= n) return;

    // Centers: uniform address -> scalar loads, L2/L1 cached.
    float c[NC];
#pragma unroll
    for (int i = 0; i < NC; ++i) c[i] = centers[i];

    const float xe = x[t];

    // phi_i = (x - c_i)^2 ; softmax(-phi) max-shift = -min(phi)
    float phi[NC];
#pragma unroll
    for (int i = 0; i < NC; ++i) {
        float d = xe - c[i];
        phi[i] = d * d;
    }
    float pmin = phi[0];
#pragma unroll
    for (int i = 1; i < NC; ++i) pmin = fminf(pmin, phi[i]);

    // w_i = exp((-phi_i) - max(-phi)) computed exactly as the reference
    // (accurate expf so the ==1.0 tie boundary matches numpy's exp).
    float w[NC];
    float sw = 0.f, swc = 0.f;
#pragma unroll
    for (int i = 0; i < NC; ++i) {
        w[i] = expf(pmin - phi[i]);
        sw  += w[i];
        swc += w[i] * c[i];
    }

    // argmax over weights, first-wins on ties (replicates jnp.argmax).
    int k = 0;
    float wb = w[0];
#pragma unroll
    for (int i = 1; i < NC; ++i) {
        if (w[i] > wb) { wb = w[i]; k = i; }
    }

    const float qs = swc / sw;
    const float qh = c[k];

    float* qbar  = out;
    float* qhard = out + (size_t)n;
    float* qsoft = out + 2 * (size_t)n;

    qbar[t]  = qs + (qh - qs);   // straight-through forward, same arithmetic as ref
    qhard[t] = qh;
    qsoft[t] = qs;

    // one_hot: wave-coordinated fully-coalesced float4 stores.
    // float4 index u = 4*waveBase + 64*j + lane  ->  elem = waveBase + 16j + lane/4,
    // quad q = lane&3.  k for that elem lives in lane 16j + lane/4.
    float4* oh4 = reinterpret_cast<float4*>(out + 3 * (size_t)n);
    const int lane = threadIdx.x & 63;
    const size_t waveBase = (size_t)(t - lane);

#pragma unroll
    for (int j = 0; j < 4; ++j) {
        int src  = 16 * j + (lane >> 2);
        int ksrc = __shfl(k, src, 64);
        int q    = lane & 3;
        float4 v;
        v.x = (ksrc == 4 * q + 0) ? 1.f : 0.f;
        v.y = (ksrc == 4 * q + 1) ? 1.f : 0.f;
        v.z = (ksrc == 4 * q + 2) ? 1.f : 0.f;
        v.w = (ksrc == 4 * q + 3) ? 1.f : 0.f;
        oh4[4 * waveBase + 64 * (size_t)j + (size_t)lane] = v;
    }
}

extern "C" void kernel_launch(void* const* d_in, const int* in_sizes, int n_in,
                              void* d_out, int out_size, void* d_ws, size_t ws_size,
                              hipStream_t stream) {
    const float* x       = (const float*)d_in[0];
    const float* centers = (const float*)d_in[1];
    float* out           = (float*)d_out;
    const int n = in_sizes[0];              // 4,194,304 (multiple of 256)
    const int blocks = (n + 255) / 256;
    quantize_kernel<<<blocks, 256, 0, stream>>>(x, centers, out, n);
}

// Round 5
// 321.367 us; speedup vs baseline: 1.0058x; 1.0058x over previous
//
#include <hip/hip_runtime.h>

// Quantize: x (16,32,32,256) fp32, 16 centers = linspace(-2,2,0.25).
// Outputs concat flat: qbar[N], qhard[N], qsoft[N], one_hot[N,16]. All fp32.
// ~319 MB writes + 17 MB reads -> memory floor ~53 us @ 6.3 TB/s.
//
// R4 post-mortem: phi-threshold argmax broke under -ffp-contract=fast
// (pmin - phi[i] fused to fma(-d,d,pmin) -> min index failed its own test ->
// m==0 -> k=-1 -> OOB c[-1]). Fix: argmax = first i with phi[i]==pmin
// (equality only, no arithmetic to contract). This is bit-identical to R3's
// passing accurate-expf argmax: distinct phi differ by >=1 ulp (>=2^-23 here),
// far beyond exp's 2^-25 rounds-to-1.0 boundary, so w==1.0 iff phi==pmin.
//
// R3 post-mortem: kernel ~118us vs 53us floor. Suspect: c[k] runtime index ->
// scratch array (rule #20), ~500MB hidden traffic. Fix: unrolled cndmask
// select for qh. qsoft uses __expf (tol 0.04 >> 2ulp).

#define NC 16

__global__ __launch_bounds__(256) void quantize_kernel(
    const float* __restrict__ x,
    const float* __restrict__ centers,
    float* __restrict__ out,
    int n)
{
    const int t = blockIdx.x * blockDim.x + threadIdx.x;
    if (t >= n) return;

    float c[NC];
#pragma unroll
    for (int i = 0; i < NC; ++i) c[i] = centers[i];

    const float xe = x[t];

    // phi_i = (x - c_i)^2 — same two ops (sub, mul) as the reference.
    float phi[NC];
#pragma unroll
    for (int i = 0; i < NC; ++i) {
        float d = xe - c[i];
        phi[i] = d * d;
    }
    float pmin = phi[0];
#pragma unroll
    for (int i = 1; i < NC; ++i) pmin = fminf(pmin, phi[i]);

    // argmax(softmax(-phi)), first-wins: first index with phi == pmin.
    // Pure equality compare — immune to FMA contraction.
    unsigned m = 0;
#pragma unroll
    for (int i = 0; i < NC; ++i) {
        m |= (unsigned)(phi[i] == pmin) << i;
    }
    const int k = m ? (__ffs(m) - 1) : 0;   // m==0 only if all-NaN; np argmax=0 then

    // qsoft: fast exp is fine at 0.04 absolute tolerance.
    float sw = 0.f, swc = 0.f;
#pragma unroll
    for (int i = 0; i < NC; ++i) {
        float w = __expf(pmin - phi[i]);
        sw  += w;
        swc += w * c[i];
    }
    const float qs = swc / sw;

    // qh = c[k] WITHOUT runtime indexing (avoids scratch spill of c[]).
    float qh = c[0];
#pragma unroll
    for (int i = 1; i < NC; ++i) qh = (k == i) ? c[i] : qh;

    float* qbar  = out;
    float* qhard = out + (size_t)n;
    float* qsoft = out + 2 * (size_t)n;

    qbar[t]  = qs + (qh - qs);   // straight-through forward, same arithmetic as ref
    qhard[t] = qh;
    qsoft[t] = qs;

    // one_hot: wave-coordinated fully-coalesced float4 stores.
    // float4 index u = 4*waveBase + 64*j + lane  ->  elem = waveBase + 16j + lane/4,
    // quad q = lane&3.  k for that elem lives in lane 16j + lane/4.
    float4* oh4 = reinterpret_cast<float4*>(out + 3 * (size_t)n);
    const int lane = threadIdx.x & 63;
    const size_t waveBase = (size_t)(t - lane);

#pragma unroll
    for (int j = 0; j < 4; ++j) {
        int src  = 16 * j + (lane >> 2);
        int ksrc = __shfl(k, src, 64);
        int q    = lane & 3;
        float4 v;
        v.x = (ksrc == 4 * q + 0) ? 1.f : 0.f;
        v.y = (ksrc == 4 * q + 1) ? 1.f : 0.f;
        v.z = (ksrc == 4 * q + 2) ? 1.f : 0.f;
        v.w = (ksrc == 4 * q + 3) ? 1.f : 0.f;
        oh4[4 * waveBase + 64 * (size_t)j + (size_t)lane] = v;
    }
}

extern "C" void kernel_launch(void* const* d_in, const int* in_sizes, int n_in,
                              void* d_out, int out_size, void* d_ws, size_t ws_size,
                              hipStream_t stream) {
    const float* x       = (const float*)d_in[0];
    const float* centers = (const float*)d_in[1];
    float* out           = (float*)d_out;
    const int n = in_sizes[0];              // 4,194,304 (multiple of 256)
    const int blocks = (n + 255) / 256;
    quantize_kernel<<<blocks, 256, 0, stream>>>(x, centers, out, n);
}

// Round 8
// 315.803 us; speedup vs baseline: 1.0235x; 1.0176x over previous
//
#include <hip/hip_runtime.h>

// Quantize: x (16,32,32,256) fp32, 16 centers = linspace(-2,2,0.25).
// Outputs concat flat: qbar[N], qhard[N], qsoft[N], one_hot[N,16]. All fp32.
// Traffic: ~319 MB writes + 17 MB reads -> floor ~53-56 us @ ~6 TB/s.
//
// R5 post-mortem: removing 16x expf + scratch c[k] moved dur_us by only 2us
// -> kernel is memory-bound (~60us; dur_us dominated by harness poison fills
// ~260us). Residual hypothesis H2: write-allocate/RFO doubling store traffic
// (would put kernel at ~112us). This round: nontemporal stores (nt flag, no
// L2 allocate) to kill RFO if present; nontemporal load for read-once x.
// If unchanged -> at roofline.
// R7 fix: __builtin_nontemporal_store rejects HIP float4 (class type) —
// use a native clang ext_vector float4 instead (legal "vector of float").

#define NC 16

typedef float f32x4 __attribute__((ext_vector_type(4)));

__global__ __launch_bounds__(256) void quantize_kernel(
    const float* __restrict__ x,
    const float* __restrict__ centers,
    float* __restrict__ out,
    int n)
{
    const int t = blockIdx.x * blockDim.x + threadIdx.x;
    if (t >= n) return;

    float c[NC];
#pragma unroll
    for (int i = 0; i < NC; ++i) c[i] = centers[i];

    const float xe = __builtin_nontemporal_load(&x[t]);

    // phi_i = (x - c_i)^2 — same two ops (sub, mul) as the reference.
    float phi[NC];
#pragma unroll
    for (int i = 0; i < NC; ++i) {
        float d = xe - c[i];
        phi[i] = d * d;
    }
    float pmin = phi[0];
#pragma unroll
    for (int i = 1; i < NC; ++i) pmin = fminf(pmin, phi[i]);

    // argmax(softmax(-phi)), first-wins: first index with phi == pmin.
    // Equality compare only — immune to FMA contraction (R4 lesson).
    unsigned m = 0;
#pragma unroll
    for (int i = 0; i < NC; ++i) {
        m |= (unsigned)(phi[i] == pmin) << i;
    }
    const int k = m ? (__ffs(m) - 1) : 0;

    // qsoft: fast exp fine at 0.04 absolute tolerance.
    float sw = 0.f, swc = 0.f;
#pragma unroll
    for (int i = 0; i < NC; ++i) {
        float w = __expf(pmin - phi[i]);
        sw  += w;
        swc += w * c[i];
    }
    const float qs = swc / sw;

    // qh = c[k] without runtime indexing (no scratch).
    float qh = c[0];
#pragma unroll
    for (int i = 1; i < NC; ++i) qh = (k == i) ? c[i] : qh;

    float* qbar  = out;
    float* qhard = out + (size_t)n;
    float* qsoft = out + 2 * (size_t)n;

    __builtin_nontemporal_store(qs + (qh - qs), &qbar[t]);
    __builtin_nontemporal_store(qh, &qhard[t]);
    __builtin_nontemporal_store(qs, &qsoft[t]);

    // one_hot: wave-coordinated fully-coalesced 16B stores (1KB/instr/wave).
    // vec4 index u = 4*waveBase + 64*j + lane  ->  elem = waveBase + 16j + lane/4,
    // quad q = lane&3.  k for that elem lives in lane 16j + lane/4.
    f32x4* oh4 = reinterpret_cast<f32x4*>(out + 3 * (size_t)n);
    const int lane = threadIdx.x & 63;
    const size_t waveBase = (size_t)(t - lane);

#pragma unroll
    for (int j = 0; j < 4; ++j) {
        int src  = 16 * j + (lane >> 2);
        int ksrc = __shfl(k, src, 64);
        int q    = lane & 3;
        f32x4 v;
        v.x = (ksrc == 4 * q + 0) ? 1.f : 0.f;
        v.y = (ksrc == 4 * q + 1) ? 1.f : 0.f;
        v.z = (ksrc == 4 * q + 2) ? 1.f : 0.f;
        v.w = (ksrc == 4 * q + 3) ? 1.f : 0.f;
        __builtin_nontemporal_store(v, &oh4[4 * waveBase + 64 * (size_t)j + (size_t)lane]);
    }
}

extern "C" void kernel_launch(void* const* d_in, const int* in_sizes, int n_in,
                              void* d_out, int out_size, void* d_ws, size_t ws_size,
                              hipStream_t stream) {
    const float* x       = (const float*)d_in[0];
    const float* centers = (const float*)d_in[1];
    float* out           = (float*)d_out;
    const int n = in_sizes[0];              // 4,194,304 (multiple of 256)
    const int blocks = (n + 255) / 256;
    quantize_kernel<<<blocks, 256, 0, stream>>>(x, centers, out, n);
}